// Round 10
// baseline (181.477 us; speedup 1.0000x reference)
//
#include <hip/hip_runtime.h>
#include <cstdint>
#include <cstddef>
#include <cmath>

#define BB 256
#define TB 2048
#define NROWS (BB*TB)          // 524288 rows of [64]
#define R1 256                 // rows per k1 tile
#define NTILE 8                // tiles per persistent block (256 blocks x 8 x 256 rows)
#define NBLK1 4096             // partial granularity: 128-row groups (bit-compat R5..R9)

typedef float f32x4 __attribute__((ext_vector_type(4)));
typedef float f32x2 __attribute__((ext_vector_type(2)));

// ---- workspace layout (bytes) ----
#define OFF_X      0ull
#define SZ_X       ((size_t)NROWS*64*4)            // 128 MiB raw x_proj [bt][h]
#define OFF_PART   (OFF_X + SZ_X)
#define SZ_PART    ((size_t)128*NBLK1*4)           // 2 MiB partials [ch][4096]
#define OFF_STAT   (OFF_PART + SZ_PART)
#define SZ_STAT    (128*8)                         // f64 col sums / sumsq
#define OFF_MASK   ((OFF_STAT + SZ_STAT + 255ull) & ~255ull)
#define SZ_MASK    ((size_t)NROWS*8)               // 4 MiB spike masks [b][t]

// async global->LDS, 16 B per lane
__device__ __forceinline__ void gll16(const float* g, void* l) {
  __builtin_amdgcn_global_load_lds(
      (const __attribute__((address_space(1))) unsigned int*)g,
      (__attribute__((address_space(3))) unsigned int*)l, 16, 0, 0);
}

// ============ K1: persistent, double-buffered A via global_load_lds ============
// 1 block/CU (144 KB LDS), 256 threads, 8 tiles x 256 rows. Stage(k+1) issued
// before compute(k) -> HBM latency hidden under FMA. Packed pk_fma core and
// 128-row partial order identical to R9 -> bit-exact.
__global__ __launch_bounds__(256) void k1_gemm(const float* __restrict__ kin,
                                               const float* __restrict__ Wsp,
                                               float* __restrict__ xproj,
                                               float* __restrict__ partials) {
  __shared__ float4 Abuf[2][R1 * 16];  // 2 x 64 KB: [r][cc ^ ((r>>3)&7)]
  __shared__ f32x4 Wp[32 * 32];        // 16 KB: [p][q ^ ((p>>2)&7)], pair-interleaved
  const int tid = threadIdx.x;
  const int ty = tid >> 3;             // 0..31 -> rows 8*ty..+7
  const int tx = tid & 7;              // col-pairs p = 4*tx..+3 (cols 8*tx..+7)
  const size_t blk0 = (size_t)blockIdx.x * NTILE;   // first tile index

  // ---- issue stage of tile 0 (async)
  {
    const float* gA = kin + blk0 * R1 * 64;
    #pragma unroll
    for (int k = 0; k < 16; ++k) {
      const int idx = k * 256 + tid;
      const int r = idx >> 4, cs = idx & 15;
      const int gq = cs ^ ((r >> 3) & 7);        // inverse of read-side swizzle
      gll16(gA + (size_t)r * 64 + gq * 4, &Abuf[0][idx]);
    }
  }
  // ---- stage W pair-interleaved (once)
  #pragma unroll
  for (int k = 0; k < 4; ++k) {
    int idx = k * 256 + tid;             // 0..1023
    int p = idx >> 5, q = idx & 31;
    float2 w0 = *(const float2*)(Wsp + (2 * p) * 64 + 2 * q);
    float2 w1 = *(const float2*)(Wsp + (2 * p + 1) * 64 + 2 * q);
    Wp[p * 32 + (q ^ ((p >> 2) & 7))] = (f32x4){w0.x, w1.x, w0.y, w1.y};
  }
  __syncthreads();                       // W + A0 resident

  #pragma unroll 1
  for (int t = 0; t < NTILE; ++t) {
    const int cur = t & 1;
    const size_t tile = blk0 + t;
    const size_t r0 = tile * R1;

    // ---- issue stage of tile t+1 into the other buffer (async, flies under compute)
    if (t + 1 < NTILE) {
      const float* gA = kin + (r0 + R1) * 64;
      #pragma unroll
      for (int k = 0; k < 16; ++k) {
        const int idx = k * 256 + tid;
        const int r = idx >> 4, cs = idx & 15;
        const int gq = cs ^ ((r >> 3) & 7);
        gll16(gA + (size_t)r * 64 + gq * 4, &Abuf[cur ^ 1][idx]);
      }
    }

    // ---- compute tile t from Abuf[cur] (R9 packed core, identical order)
    const float4* As = Abuf[cur];
    f32x2 acc2[8][4];
    #pragma unroll
    for (int i = 0; i < 8; ++i)
      #pragma unroll
      for (int jp = 0; jp < 4; ++jp) acc2[i][jp] = (f32x2){0.f, 0.f};

    #pragma unroll 1
    for (int cc = 0; cc < 16; ++cc) {
      float4 av[8];
      f32x4 q0[4], q1[4];
      #pragma unroll
      for (int i = 0; i < 8; ++i)
        av[i] = As[(8 * ty + i) * 16 + (cc ^ (ty & 7))];
      #pragma unroll
      for (int jp = 0; jp < 4; ++jp) {
        const int p = 4 * tx + jp;
        q0[jp] = Wp[p * 32 + ((2 * cc)     ^ tx)];
        q1[jp] = Wp[p * 32 + ((2 * cc + 1) ^ tx)];
      }
      #pragma unroll
      for (int i = 0; i < 8; ++i) {
        #pragma unroll
        for (int jp = 0; jp < 4; ++jp) {
          acc2[i][jp] = __builtin_elementwise_fma((f32x2){av[i].x, av[i].x}, q0[jp].xy, acc2[i][jp]);
          acc2[i][jp] = __builtin_elementwise_fma((f32x2){av[i].y, av[i].y}, q0[jp].zw, acc2[i][jp]);
          acc2[i][jp] = __builtin_elementwise_fma((f32x2){av[i].z, av[i].z}, q1[jp].xy, acc2[i][jp]);
          acc2[i][jp] = __builtin_elementwise_fma((f32x2){av[i].w, av[i].w}, q1[jp].zw, acc2[i][jp]);
        }
      }
    }

    #pragma unroll
    for (int i = 0; i < 8; ++i) {
      const size_t row = r0 + 8 * ty + i;
      f32x4 lo = {acc2[i][0].x, acc2[i][0].y, acc2[i][1].x, acc2[i][1].y};
      f32x4 hi = {acc2[i][2].x, acc2[i][2].y, acc2[i][3].x, acc2[i][3].y};
      *(f32x4*)(xproj + row * 64 + 8 * tx)     = lo;
      *(f32x4*)(xproj + row * 64 + 8 * tx + 4) = hi;
    }

    __syncthreads();   // b1: all waves done reading Abuf[cur]; stage(t+1) drained

    // ---- stats into scratch = dead Abuf[cur] (identical value order to R9)
    float* Sm = (float*)Abuf[cur];       // [64][33]
    float* Sq = Sm + 64 * 33;
    #pragma unroll
    for (int j = 0; j < 8; ++j) {
      const int col = 8 * tx + j;
      float s = 0.f, q = 0.f;
      #pragma unroll
      for (int i = 0; i < 8; ++i) {      // rows ascending within group
        float v = (j & 1) ? acc2[i][j >> 1].y : acc2[i][j >> 1].x;
        s += v;
        q += v * v;
      }
      Sm[col * 33 + ty] = s;
      Sq[col * 33 + ty] = q;
    }
    __syncthreads();   // b2
    if (tid < 64) {
      float s0 = 0.f, q0 = 0.f, s1 = 0.f, q1 = 0.f;
      #pragma unroll
      for (int g = 0; g < 16; ++g)  { s0 += Sm[tid * 33 + g]; q0 += Sq[tid * 33 + g]; }
      #pragma unroll
      for (int g = 16; g < 32; ++g) { s1 += Sm[tid * 33 + g]; q1 += Sq[tid * 33 + g]; }
      const size_t p0 = 2 * tile;
      partials[(size_t)tid * NBLK1 + p0]            = s0;
      partials[(size_t)tid * NBLK1 + p0 + 1]        = s1;
      partials[(size_t)(64 + tid) * NBLK1 + p0]     = q0;
      partials[(size_t)(64 + tid) * NBLK1 + p0 + 1] = q1;
    }
    __syncthreads();   // b3: protect scratch from next tile's stage issue
  }
}

// ============ K2a: deterministic f64 reduction (coalesced rows) ============
__global__ __launch_bounds__(256) void k2a_reduce(const float* __restrict__ partials,
                                                  double* __restrict__ statd) {
  __shared__ double sd[256];
  const int idx = blockIdx.x;              // 0..127
  double acc = 0.0;
  for (int k = threadIdx.x; k < NBLK1; k += 256)
    acc += (double)partials[(size_t)idx * NBLK1 + k];
  sd[threadIdx.x] = acc;
  __syncthreads();
  for (int s = 128; s > 0; s >>= 1) {
    if (threadIdx.x < s) sd[threadIdx.x] += sd[threadIdx.x + s];
    __syncthreads();
  }
  if (threadIdx.x == 0) statd[idx] = sd[0];
}

// ============ K3: layer-1 LIF scan; scale/shift derived in-kernel ============
#define K3_LOAD(BUF, TBASE)                         \
  { _Pragma("unroll") for (int i_ = 0; i_ < 64; ++i_) \
      BUF[i_] = xr[(size_t)((TBASE) + i_) * 64]; }

#define K3_CHUNK(CUR, NXT0, TBASE)                                   \
  { unsigned long long keep = 0;                                     \
    _Pragma("unroll") for (int i_ = 0; i_ < 64; ++i_) {              \
      bool sp = (mem >= 1.0f);                                       \
      unsigned long long mb = __ballot(sp);                          \
      if (h == i_) keep = mb;                                        \
      float xrn = (i_ < 63) ? CUR[(i_ + 1) & 63] : (NXT0);           \
      float xn = fmaf(xrn, sc, sh);                                  \
      mem = sp ? xn : fmaf(mem, 0.9f, xn);                           \
    }                                                                \
    masksB[(size_t)b * TB + (TBASE) + h] = keep; }

__global__ __launch_bounds__(64) void k3_scan1(const float* __restrict__ xproj,
                                               const double* __restrict__ statd,
                                               const float* __restrict__ gamma,
                                               const float* __restrict__ beta,
                                               unsigned long long* __restrict__ masksB) {
  const int b = blockIdx.x, h = threadIdx.x;
  const double mean = statd[h] / (double)NROWS;
  const double ex2  = statd[64 + h] / (double)NROWS;
  const double var  = ex2 - mean * mean;
  const double scd  = (double)gamma[h] / sqrt(var + 1e-5);
  const float sc = (float)scd;
  const float sh = (float)((double)beta[h] - mean * scd);

  const float* xr = xproj + (size_t)b * TB * 64 + h;
  float xa[64], xb[64];

  K3_LOAD(xa, 0)
  float mem = fmaf(xa[0], sc, sh);   // t=0 post-add state

  #pragma unroll 1
  for (int t0 = 0; t0 < TB; t0 += 128) {
    K3_LOAD(xb, t0 + 64)
    K3_CHUNK(xa, xb[0], t0)
    if (t0 + 128 < TB) { K3_LOAD(xa, t0 + 128) }
    K3_CHUNK(xb, xa[0], t0 + 64)    // final chunk: trailing xa[0] is dead
  }
}

// ============ K45: fused cur2 (LDS) + layer-2 scan; thresholds in-kernel ============
#define K45_LOAD(BUF, TBASE)                                             \
  { _Pragma("unroll") for (int k_ = 0; k_ < 16; ++k_) {                  \
      f32x4 v = *(const f32x4*)(cr + (TBASE) + 4 * k_);                  \
      BUF[4 * k_] = v.x; BUF[4 * k_ + 1] = v.y;                          \
      BUF[4 * k_ + 2] = v.z; BUF[4 * k_ + 3] = v.w; } }

#define K45_CHUNK(CUR, NXT0)                                  \
  { _Pragma("unroll") for (int i_ = 0; i_ < 64; ++i_) {       \
      bool sp = (mem >= th);                                  \
      cnt += sp ? 1u : 0u;                                    \
      float xn = (i_ < 63) ? CUR[(i_ + 1) & 63] : (NXT0);     \
      mem = sp ? xn : fmaf(mem, 0.9f, xn);                    \
    } }

__global__ __launch_bounds__(256) void k45_cur2scan(const unsigned long long* __restrict__ masksB,
                                                    const float* __restrict__ Wc,
                                                    const float* __restrict__ lat,
                                                    const float* __restrict__ tda,
                                                    const float* __restrict__ Wtda,
                                                    const float* __restrict__ btda,
                                                    float* __restrict__ out) {
  __shared__ float WcL[256];
  __shared__ float latL[16];
  __shared__ float thL[4];
  __shared__ float lbuf[4][TB + 4];     // padded rows
  const int tid = threadIdx.x, b = blockIdx.x;
  WcL[tid] = Wc[tid];
  if (tid < 16) latL[tid] = lat[tid];
  if (tid >= 32 && tid < 36) {
    const int j = tid - 32;
    double acc = (double)btda[j];
    for (int k = 0; k < 50; ++k)
      acc += (double)tda[b * 50 + k] * (double)Wtda[j * 50 + k];
    double sig = 1.0 / (1.0 + exp(-acc));
    thL[j] = (float)(1.0 + 0.5 * sig);
  }
  __syncthreads();

  // phase 1: cur2 for all t (identical math to old k4), into LDS
  #pragma unroll 1
  for (int c = 0; c < 8; ++c) {
    const int t = c * 256 + tid;
    const unsigned long long m = masksB[(size_t)b * TB + t];
    const unsigned lo = (unsigned)m, hi = (unsigned)(m >> 32);
    float v0 = 0.f, v1 = 0.f, v2 = 0.f, v3 = 0.f;
    #pragma unroll
    for (int hh = 0; hh < 32; ++hh) {
      const float bit = (float)((lo >> hh) & 1u);
      v0 = fmaf(bit, WcL[hh],       v0);
      v1 = fmaf(bit, WcL[64 + hh],  v1);
      v2 = fmaf(bit, WcL[128 + hh], v2);
      v3 = fmaf(bit, WcL[192 + hh], v3);
    }
    #pragma unroll
    for (int hh = 32; hh < 64; ++hh) {
      const float bit = (float)((hi >> (hh - 32)) & 1u);
      v0 = fmaf(bit, WcL[hh],       v0);
      v1 = fmaf(bit, WcL[64 + hh],  v1);
      v2 = fmaf(bit, WcL[128 + hh], v2);
      v3 = fmaf(bit, WcL[192 + hh], v3);
    }
    { float cx = v0 * latL[0];  cx = fmaf(v1, latL[4],  cx); cx = fmaf(v2, latL[8],  cx); cx = fmaf(v3, latL[12], cx); lbuf[0][t] = cx; }
    { float cx = v0 * latL[1];  cx = fmaf(v1, latL[5],  cx); cx = fmaf(v2, latL[9],  cx); cx = fmaf(v3, latL[13], cx); lbuf[1][t] = cx; }
    { float cx = v0 * latL[2];  cx = fmaf(v1, latL[6],  cx); cx = fmaf(v2, latL[10], cx); cx = fmaf(v3, latL[14], cx); lbuf[2][t] = cx; }
    { float cx = v0 * latL[3];  cx = fmaf(v1, latL[7],  cx); cx = fmaf(v2, latL[11], cx); cx = fmaf(v3, latL[15], cx); lbuf[3][t] = cx; }
  }
  __syncthreads();
  if (tid >= 64) return;

  // phase 2: wave 0 scans from LDS; lanes mirror 4 chains (identical math)
  const int j4 = tid & 3;
  const float th = thL[j4];
  const float* cr = lbuf[j4];
  float ca[64], cb[64];

  K45_LOAD(ca, 0)
  float mem = ca[0];
  unsigned cnt = 0;

  #pragma unroll 1
  for (int t0 = 0; t0 < TB; t0 += 128) {
    K45_LOAD(cb, t0 + 64)
    K45_CHUNK(ca, cb[0])
    if (t0 + 128 < TB) { K45_LOAD(ca, t0 + 128) }
    K45_CHUNK(cb, ca[0])
  }
  if (tid < 4) out[b * 4 + j4] = (float)cnt;
}

extern "C" void kernel_launch(void* const* d_in, const int* in_sizes, int n_in,
                              void* d_out, int out_size, void* d_ws, size_t ws_size,
                              hipStream_t stream) {
  const float* kin   = (const float*)d_in[0];
  const float* tda   = (const float*)d_in[1];
  const float* Wsp   = (const float*)d_in[2];
  const float* gamma = (const float*)d_in[3];
  const float* beta  = (const float*)d_in[4];
  const float* Wc    = (const float*)d_in[5];
  const float* lat   = (const float*)d_in[6];
  const float* Wtda  = (const float*)d_in[7];
  const float* btda  = (const float*)d_in[8];

  char* ws = (char*)d_ws;
  float*  xproj    = (float*)(ws + OFF_X);
  float*  partials = (float*)(ws + OFF_PART);
  double* statd    = (double*)(ws + OFF_STAT);
  unsigned long long* masksB = (unsigned long long*)(ws + OFF_MASK);
  float*  out      = (float*)d_out;

  k1_gemm  <<<dim3(256),   dim3(256), 0, stream>>>(kin, Wsp, xproj, partials);
  k2a_reduce<<<dim3(128),  dim3(256), 0, stream>>>(partials, statd);
  k3_scan1 <<<dim3(BB),    dim3(64),  0, stream>>>(xproj, statd, gamma, beta, masksB);
  k45_cur2scan<<<dim3(BB), dim3(256), 0, stream>>>(masksB, Wc, lat, tda, Wtda, btda, out);
}

// Round 11
// 179.343 us; speedup vs baseline: 1.0119x; 1.0119x over previous
//
#include <hip/hip_runtime.h>
#include <cstdint>
#include <cstddef>
#include <cmath>

#define BB 256
#define TB 2048
#define NROWS (BB*TB)          // 524288 rows of [64]
#define RT 128                 // rows per k1 tile
#define NT1 8                  // tiles per block
#define GRID1 512              // blocks (512*8*128 = NROWS)
#define NBLK1 4096             // partial granularity: 128-row groups (bit-compat R5..R10)

typedef float f32x4 __attribute__((ext_vector_type(4)));
typedef float f32x2 __attribute__((ext_vector_type(2)));

// ---- workspace layout (bytes) ----
#define OFF_X      0ull
#define SZ_X       ((size_t)NROWS*64*4)            // 128 MiB raw x_proj [bt][h]
#define OFF_PART   (OFF_X + SZ_X)
#define SZ_PART    ((size_t)128*NBLK1*4)           // 2 MiB partials [ch][4096]
#define OFF_STAT   (OFF_PART + SZ_PART)
#define SZ_STAT    (128*8)                         // f64 col sums / sumsq
#define OFF_MASK   ((OFF_STAT + SZ_STAT + 255ull) & ~255ull)
#define SZ_MASK    ((size_t)NROWS*8)               // 4 MiB spike masks [b][t]

// async global->LDS, 16 B per lane
__device__ __forceinline__ void gll16(const float* g, void* l) {
  __builtin_amdgcn_global_load_lds(
      (const __attribute__((address_space(1))) unsigned int*)g,
      (__attribute__((address_space(3))) unsigned int*)l, 16, 0, 0);
}

// ============ K1: pipelined GEMM, counted-vmcnt + raw-barrier (T3/T4) ============
// 512 blocks x 128 thr (2 waves); 8 tiles x 128 rows; A dbuf 2x32KB via
// global_load_lds (wave-private halves -> no barriers on A path); W 16KB LDS.
// Thread tile 8x8, ty 0..15 -> FMA and stat trees bit-identical to R5..R9.
__global__ __launch_bounds__(128) void k1_gemm(const float* __restrict__ kin,
                                               const float* __restrict__ Wsp,
                                               float* __restrict__ xproj,
                                               float* __restrict__ partials) {
  __shared__ float4 Abuf[2][RT * 16];  // 2 x 32 KB: [r][cs ^ ((r>>3)&7)]
  __shared__ f32x4 Wp[32 * 32];        // 16 KB: [p][q ^ ((p>>2)&7)], pair-interleaved
  const int tid = threadIdx.x;
  const int ty = tid >> 3;             // 0..15 -> rows 8*ty..+7
  const int tx = tid & 7;              // col-pairs p = 4*tx..+3 (cols 8*tx..+7)
  const int wv = tid >> 6;             // wave 0/1: owns rows 64*wv..64*wv+63
  const int lt = tid & 63;
  const size_t row0 = (size_t)blockIdx.x * (NT1 * RT);

  // ---- stage W pair-interleaved (once): (p,q) = {W[2p][2q],W[2p+1][2q],W[2p][2q+1],W[2p+1][2q+1]}
  #pragma unroll
  for (int k = 0; k < 8; ++k) {
    int idx = k * 128 + tid;             // 0..1023
    int p = idx >> 5, q = idx & 31;
    float2 w0 = *(const float2*)(Wsp + (2 * p) * 64 + 2 * q);
    float2 w1 = *(const float2*)(Wsp + (2 * p + 1) * 64 + 2 * q);
    Wp[p * 32 + (q ^ ((p >> 2) & 7))] = (f32x4){w0.x, w1.x, w0.y, w1.y};
  }
  __syncthreads();                       // W resident (drains W loads only)

  // ---- issue-A macro: wave stages its own 64-row half of tile TT into buf BB_
  //      slot idx -> r=idx>>4, cs=idx&15; global chunk gq = cs ^ ((r>>3)&7)
#define ISSUE_A(TT, BB_)                                                     \
  { const float* gA = kin + (row0 + (size_t)(TT) * RT) * 64;                 \
    _Pragma("unroll") for (int k_ = 0; k_ < 16; ++k_) {                      \
      const int idx = wv * 1024 + k_ * 64 + lt;                              \
      const int r_ = idx >> 4, cs_ = idx & 15;                               \
      const int gq_ = cs_ ^ ((r_ >> 3) & 7);                                 \
      gll16(gA + (size_t)r_ * 64 + gq_ * 4, &Abuf[BB_][idx]);                \
    } }

  ISSUE_A(0, 0)

  #pragma unroll
  for (int t = 0; t < NT1; ++t) {
    const int cur = t & 1;
    if (t + 1 < NT1) ISSUE_A(t + 1, cur ^ 1)

    // wait: tile-t loads landed; younger ops (S(t-1), L(t+1)) may stay in flight
    if (t == 0 || t == NT1 - 1) {
      asm volatile("s_waitcnt vmcnt(16)" ::: "memory");
    } else {
      asm volatile("s_waitcnt vmcnt(32)" ::: "memory");
    }

    // ---- compute tile t (R9 packed core; wave reads only its own half)
    const float4* As = Abuf[cur];
    f32x2 acc2[8][4];
    #pragma unroll
    for (int i = 0; i < 8; ++i)
      #pragma unroll
      for (int jp = 0; jp < 4; ++jp) acc2[i][jp] = (f32x2){0.f, 0.f};

    #pragma unroll 1
    for (int cc = 0; cc < 16; ++cc) {
      float4 av[8];
      f32x4 q0[4], q1[4];
      #pragma unroll
      for (int i = 0; i < 8; ++i)
        av[i] = As[(8 * ty + i) * 16 + (cc ^ (ty & 7))];
      #pragma unroll
      for (int jp = 0; jp < 4; ++jp) {
        const int p = 4 * tx + jp;
        q0[jp] = Wp[p * 32 + ((2 * cc)     ^ tx)];
        q1[jp] = Wp[p * 32 + ((2 * cc + 1) ^ tx)];
      }
      #pragma unroll
      for (int i = 0; i < 8; ++i) {
        #pragma unroll
        for (int jp = 0; jp < 4; ++jp) {
          acc2[i][jp] = __builtin_elementwise_fma((f32x2){av[i].x, av[i].x}, q0[jp].xy, acc2[i][jp]);
          acc2[i][jp] = __builtin_elementwise_fma((f32x2){av[i].y, av[i].y}, q0[jp].zw, acc2[i][jp]);
          acc2[i][jp] = __builtin_elementwise_fma((f32x2){av[i].z, av[i].z}, q1[jp].xy, acc2[i][jp]);
          acc2[i][jp] = __builtin_elementwise_fma((f32x2){av[i].w, av[i].w}, q1[jp].zw, acc2[i][jp]);
        }
      }
    }

    const size_t tile_r0 = row0 + (size_t)t * RT;
    #pragma unroll
    for (int i = 0; i < 8; ++i) {
      const size_t row = tile_r0 + 8 * ty + i;
      f32x4 lo = {acc2[i][0].x, acc2[i][0].y, acc2[i][1].x, acc2[i][1].y};
      f32x4 hi = {acc2[i][2].x, acc2[i][2].y, acc2[i][3].x, acc2[i][3].y};
      *(f32x4*)(xproj + row * 64 + 8 * tx)     = lo;
      *(f32x4*)(xproj + row * 64 + 8 * tx + 4) = hi;
    }

    // ---- stats into scratch = dead Abuf[cur]; raw barriers (no vmcnt drain)
    __builtin_amdgcn_s_barrier();        // both waves done reading Abuf[cur]
    float* Sm = (float*)Abuf[cur];       // [64][17]
    float* Sq = Sm + 64 * 17;
    #pragma unroll
    for (int j = 0; j < 8; ++j) {
      const int col = 8 * tx + j;
      float s = 0.f, q = 0.f;
      #pragma unroll
      for (int i = 0; i < 8; ++i) {      // rows ascending within 8-row group
        float v = (j & 1) ? acc2[i][j >> 1].y : acc2[i][j >> 1].x;
        s += v;
        q += v * v;
      }
      Sm[col * 17 + ty] = s;
      Sq[col * 17 + ty] = q;
    }
    asm volatile("s_waitcnt lgkmcnt(0)" ::: "memory");
    __builtin_amdgcn_s_barrier();        // stats visible to wave 0
    if (tid < 64) {
      float s = 0.f, q = 0.f;
      #pragma unroll
      for (int g = 0; g < 16; ++g) {     // g ascending -> rows 0..127 in order
        s += Sm[tid * 17 + g];
        q += Sq[tid * 17 + g];
      }
      const size_t pg = (size_t)blockIdx.x * NT1 + t;   // 128-row group index
      partials[(size_t)tid * NBLK1 + pg]        = s;
      partials[(size_t)(64 + tid) * NBLK1 + pg] = q;
    }
    asm volatile("s_waitcnt lgkmcnt(0)" ::: "memory");
    __builtin_amdgcn_s_barrier();        // scratch reads done before next ISSUE_A
  }
#undef ISSUE_A
}

// ============ K2a: deterministic f64 reduction (coalesced rows) ============
__global__ __launch_bounds__(256) void k2a_reduce(const float* __restrict__ partials,
                                                  double* __restrict__ statd) {
  __shared__ double sd[256];
  const int idx = blockIdx.x;              // 0..127
  double acc = 0.0;
  for (int k = threadIdx.x; k < NBLK1; k += 256)
    acc += (double)partials[(size_t)idx * NBLK1 + k];
  sd[threadIdx.x] = acc;
  __syncthreads();
  for (int s = 128; s > 0; s >>= 1) {
    if (threadIdx.x < s) sd[threadIdx.x] += sd[threadIdx.x + s];
    __syncthreads();
  }
  if (threadIdx.x == 0) statd[idx] = sd[0];
}

// ============ K3: layer-1 LIF scan; scale/shift derived in-kernel ============
#define K3_LOAD(BUF, TBASE)                         \
  { _Pragma("unroll") for (int i_ = 0; i_ < 64; ++i_) \
      BUF[i_] = xr[(size_t)((TBASE) + i_) * 64]; }

#define K3_CHUNK(CUR, NXT0, TBASE)                                   \
  { unsigned long long keep = 0;                                     \
    _Pragma("unroll") for (int i_ = 0; i_ < 64; ++i_) {              \
      bool sp = (mem >= 1.0f);                                       \
      unsigned long long mb = __ballot(sp);                          \
      if (h == i_) keep = mb;                                        \
      float xrn = (i_ < 63) ? CUR[(i_ + 1) & 63] : (NXT0);           \
      float xn = fmaf(xrn, sc, sh);                                  \
      mem = sp ? xn : fmaf(mem, 0.9f, xn);                           \
    }                                                                \
    masksB[(size_t)b * TB + (TBASE) + h] = keep; }

__global__ __launch_bounds__(64) void k3_scan1(const float* __restrict__ xproj,
                                               const double* __restrict__ statd,
                                               const float* __restrict__ gamma,
                                               const float* __restrict__ beta,
                                               unsigned long long* __restrict__ masksB) {
  const int b = blockIdx.x, h = threadIdx.x;
  const double mean = statd[h] / (double)NROWS;
  const double ex2  = statd[64 + h] / (double)NROWS;
  const double var  = ex2 - mean * mean;
  const double scd  = (double)gamma[h] / sqrt(var + 1e-5);
  const float sc = (float)scd;
  const float sh = (float)((double)beta[h] - mean * scd);

  const float* xr = xproj + (size_t)b * TB * 64 + h;
  float xa[64], xb[64];

  K3_LOAD(xa, 0)
  float mem = fmaf(xa[0], sc, sh);   // t=0 post-add state

  #pragma unroll 1
  for (int t0 = 0; t0 < TB; t0 += 128) {
    K3_LOAD(xb, t0 + 64)
    K3_CHUNK(xa, xb[0], t0)
    if (t0 + 128 < TB) { K3_LOAD(xa, t0 + 128) }
    K3_CHUNK(xb, xa[0], t0 + 64)    // final chunk: trailing xa[0] is dead
  }
}

// ============ K45: fused cur2 (LDS) + layer-2 scan; thresholds in-kernel ============
#define K45_LOAD(BUF, TBASE)                                             \
  { _Pragma("unroll") for (int k_ = 0; k_ < 16; ++k_) {                  \
      f32x4 v = *(const f32x4*)(cr + (TBASE) + 4 * k_);                  \
      BUF[4 * k_] = v.x; BUF[4 * k_ + 1] = v.y;                          \
      BUF[4 * k_ + 2] = v.z; BUF[4 * k_ + 3] = v.w; } }

#define K45_CHUNK(CUR, NXT0)                                  \
  { _Pragma("unroll") for (int i_ = 0; i_ < 64; ++i_) {       \
      bool sp = (mem >= th);                                  \
      cnt += sp ? 1u : 0u;                                    \
      float xn = (i_ < 63) ? CUR[(i_ + 1) & 63] : (NXT0);     \
      mem = sp ? xn : fmaf(mem, 0.9f, xn);                    \
    } }

__global__ __launch_bounds__(256) void k45_cur2scan(const unsigned long long* __restrict__ masksB,
                                                    const float* __restrict__ Wc,
                                                    const float* __restrict__ lat,
                                                    const float* __restrict__ tda,
                                                    const float* __restrict__ Wtda,
                                                    const float* __restrict__ btda,
                                                    float* __restrict__ out) {
  __shared__ float WcL[256];
  __shared__ float latL[16];
  __shared__ float thL[4];
  __shared__ float lbuf[4][TB + 4];     // padded rows
  const int tid = threadIdx.x, b = blockIdx.x;
  WcL[tid] = Wc[tid];
  if (tid < 16) latL[tid] = lat[tid];
  if (tid >= 32 && tid < 36) {
    const int j = tid - 32;
    double acc = (double)btda[j];
    for (int k = 0; k < 50; ++k)
      acc += (double)tda[b * 50 + k] * (double)Wtda[j * 50 + k];
    double sig = 1.0 / (1.0 + exp(-acc));
    thL[j] = (float)(1.0 + 0.5 * sig);
  }
  __syncthreads();

  // phase 1: cur2 for all t (identical math to old k4), into LDS
  #pragma unroll 1
  for (int c = 0; c < 8; ++c) {
    const int t = c * 256 + tid;
    const unsigned long long m = masksB[(size_t)b * TB + t];
    const unsigned lo = (unsigned)m, hi = (unsigned)(m >> 32);
    float v0 = 0.f, v1 = 0.f, v2 = 0.f, v3 = 0.f;
    #pragma unroll
    for (int hh = 0; hh < 32; ++hh) {
      const float bit = (float)((lo >> hh) & 1u);
      v0 = fmaf(bit, WcL[hh],       v0);
      v1 = fmaf(bit, WcL[64 + hh],  v1);
      v2 = fmaf(bit, WcL[128 + hh], v2);
      v3 = fmaf(bit, WcL[192 + hh], v3);
    }
    #pragma unroll
    for (int hh = 32; hh < 64; ++hh) {
      const float bit = (float)((hi >> (hh - 32)) & 1u);
      v0 = fmaf(bit, WcL[hh],       v0);
      v1 = fmaf(bit, WcL[64 + hh],  v1);
      v2 = fmaf(bit, WcL[128 + hh], v2);
      v3 = fmaf(bit, WcL[192 + hh], v3);
    }
    { float cx = v0 * latL[0];  cx = fmaf(v1, latL[4],  cx); cx = fmaf(v2, latL[8],  cx); cx = fmaf(v3, latL[12], cx); lbuf[0][t] = cx; }
    { float cx = v0 * latL[1];  cx = fmaf(v1, latL[5],  cx); cx = fmaf(v2, latL[9],  cx); cx = fmaf(v3, latL[13], cx); lbuf[1][t] = cx; }
    { float cx = v0 * latL[2];  cx = fmaf(v1, latL[6],  cx); cx = fmaf(v2, latL[10], cx); cx = fmaf(v3, latL[14], cx); lbuf[2][t] = cx; }
    { float cx = v0 * latL[3];  cx = fmaf(v1, latL[7],  cx); cx = fmaf(v2, latL[11], cx); cx = fmaf(v3, latL[15], cx); lbuf[3][t] = cx; }
  }
  __syncthreads();
  if (tid >= 64) return;

  // phase 2: wave 0 scans from LDS; lanes mirror 4 chains (identical math)
  const int j4 = tid & 3;
  const float th = thL[j4];
  const float* cr = lbuf[j4];
  float ca[64], cb[64];

  K45_LOAD(ca, 0)
  float mem = ca[0];
  unsigned cnt = 0;

  #pragma unroll 1
  for (int t0 = 0; t0 < TB; t0 += 128) {
    K45_LOAD(cb, t0 + 64)
    K45_CHUNK(ca, cb[0])
    if (t0 + 128 < TB) { K45_LOAD(ca, t0 + 128) }
    K45_CHUNK(cb, ca[0])
  }
  if (tid < 4) out[b * 4 + j4] = (float)cnt;
}

extern "C" void kernel_launch(void* const* d_in, const int* in_sizes, int n_in,
                              void* d_out, int out_size, void* d_ws, size_t ws_size,
                              hipStream_t stream) {
  const float* kin   = (const float*)d_in[0];
  const float* tda   = (const float*)d_in[1];
  const float* Wsp   = (const float*)d_in[2];
  const float* gamma = (const float*)d_in[3];
  const float* beta  = (const float*)d_in[4];
  const float* Wc    = (const float*)d_in[5];
  const float* lat   = (const float*)d_in[6];
  const float* Wtda  = (const float*)d_in[7];
  const float* btda  = (const float*)d_in[8];

  char* ws = (char*)d_ws;
  float*  xproj    = (float*)(ws + OFF_X);
  float*  partials = (float*)(ws + OFF_PART);
  double* statd    = (double*)(ws + OFF_STAT);
  unsigned long long* masksB = (unsigned long long*)(ws + OFF_MASK);
  float*  out      = (float*)d_out;

  k1_gemm  <<<dim3(GRID1),  dim3(128), 0, stream>>>(kin, Wsp, xproj, partials);
  k2a_reduce<<<dim3(128),   dim3(256), 0, stream>>>(partials, statd);
  k3_scan1 <<<dim3(BB),     dim3(64),  0, stream>>>(xproj, statd, gamma, beta, masksB);
  k45_cur2scan<<<dim3(BB),  dim3(256), 0, stream>>>(masksB, Wc, lat, tda, Wtda, btda, out);
}